// Round 23
// baseline (49.908 us; speedup 1.0000x reference)
//
#include <hip/hip_runtime.h>
#include <hip/hip_bf16.h>

#define NPTS 32768
#define NSLAB 16
#define NF 128
#define HDIM 128
#define KDIM 512          // 4*NF
#define PTS_PER_BLK 64
#define MAXBLK 2064       // sum ceil(count_s/64) <= 4*32768/64 + 16

// ---- workspace layout (bytes) ----
// [0, 64)        : g_count[16] (int)
// [1024, +1MB)   : lists, u16 [16][NPTS]
// [4MB, 6MB)     : W1T bf16 [16][128][512]  (K-permuted: k' = f*4+type)
// [6MB, 6.5MB)   : W2T bf16 [16][128][128]
#define WS_COUNT_OFF   0
#define WS_LIST_OFF    1024
#define WS_W1T_OFF     (4u << 20)
#define WS_W2T_OFF     (6u << 20)

typedef __attribute__((ext_vector_type(8))) short bf16x8;
typedef __attribute__((ext_vector_type(4))) float f32x4;
typedef __attribute__((ext_vector_type(4))) unsigned int u32x4;
typedef __attribute__((ext_vector_type(2))) unsigned int u32x2;

__device__ __forceinline__ unsigned short f2bf(float f) {
    union { float f; unsigned u; } v; v.f = f;
    unsigned u = v.u;
    return (unsigned short)((u + 0x7FFFu + ((u >> 16) & 1u)) >> 16);
}
__device__ __forceinline__ float fast_tanh(float v) {
    v = fminf(fmaxf(v, -15.0f), 15.0f);
    float t = __builtin_amdgcn_exp2f(v * 2.8853900817779268f); // e^{2v}
    return (t - 1.0f) * __builtin_amdgcn_rcpf(t + 1.0f);
}
// pack two f32 -> one u32 of two bf16 (lo = a, hi = b)
__device__ __forceinline__ unsigned pk_bf16(float a, float b) {
    unsigned r;
    asm("v_cvt_pk_bf16_f32 %0, %1, %2" : "=v"(r) : "v"(a), "v"(b));
    return r;
}

// Transpose + f32->bf16 for W1 (K-permuted) and W2 in one launch (r13/r15-proven).
// Also zeroes g_count (runs before build_lists on the stream).
__global__ void prep_weights(const float* __restrict__ W1, const float* __restrict__ W2,
                             unsigned short* __restrict__ W1T, unsigned short* __restrict__ W2T,
                             int* __restrict__ g_count) {
    if (blockIdx.x == 0 && blockIdx.y == 0 && threadIdx.x < NSLAB)
        g_count[threadIdx.x] = 0;
    __shared__ float tl[32][33];
    int s = blockIdx.y;
    int bt = blockIdx.x;
    const float* in; unsigned short* out; int K, N, perm, tk, tn;
    if (bt < 64) { in = W1; out = W1T; K = KDIM; N = HDIM; perm = 1; tk = bt >> 2; tn = bt & 3; }
    else         { bt -= 64; in = W2; out = W2T; K = HDIM; N = HDIM; perm = 0; tk = bt >> 2; tn = bt & 3; }
    const float* ins = in + (size_t)s * K * N;
    unsigned short* outs = out + (size_t)s * N * K;
    int t = threadIdx.x, r4 = t >> 5, c = t & 31;
    #pragma unroll
    for (int i = 0; i < 4; ++i) {
        int r = i * 8 + r4;
        tl[r][c] = ins[(tk * 32 + r) * N + tn * 32 + c];
    }
    __syncthreads();
    #pragma unroll
    for (int i = 0; i < 4; ++i) {
        int r = i * 8 + r4;
        int k = tk * 32 + c;
        int kp = perm ? ((k & 127) * 4 + (k >> 7)) : k;
        outs[(size_t)(tn * 32 + r) * K + kp] = f2bf(tl[c][r]);
    }
}

// build_lists also zeroes out[] (stream-ordered before mlp_eval's atomics).
__global__ void build_lists(const float* __restrict__ x,
                            const float* __restrict__ mids,
                            const float* __restrict__ widths,
                            int* __restrict__ g_count,
                            unsigned short* __restrict__ lists,
                            float* __restrict__ out) {
    __shared__ int cnt[NSLAB];
    __shared__ int base[NSLAB];
    int tid = threadIdx.x;
    if (tid < NSLAB) cnt[tid] = 0;
    __syncthreads();
    int n = blockIdx.x * 256 + tid;
    out[n] = 0.0f;
    float xc = x[n * 6];
    int ofs[NSLAB];
    unsigned int amask = 0;
    #pragma unroll
    for (int s = 0; s < NSLAB; ++s) {
        float xmin = mids[s] - 0.5f * widths[s];
        float xmax = mids[s] + 0.5f * widths[s];
        if (xc >= xmin && xc <= xmax) {
            ofs[s] = atomicAdd(&cnt[s], 1);
            amask |= (1u << s);
        }
    }
    __syncthreads();
    if (tid < NSLAB) base[tid] = atomicAdd(&g_count[tid], cnt[tid]);
    __syncthreads();
    #pragma unroll
    for (int s = 0; s < NSLAB; ++s)
        if (amask & (1u << s))
            lists[s * NPTS + base[s] + ofs[s]] = (unsigned short)n;
}

// Block: 256 thr = 4 waves; 64 points x 1 slab. Work item via inline prefix scan.
// r22-proven body minus setprio (lockstep waves: m190 regime) with chunk-7 peel:
// W2 half0 loads issued before COMPUTE(7); hbuf written without the c7 barrier
// (wave-private region; cross-wave buf0 reads ended at the c6 barrier).
__global__ __launch_bounds__(256, 4) void mlp_eval(
        const float* __restrict__ x,  const float* __restrict__ B,
        const unsigned short* __restrict__ W1T, const float* __restrict__ b1,
        const unsigned short* __restrict__ W2T, const float* __restrict__ b2,
        const float* __restrict__ W3, const float* __restrict__ b3,
        const float* __restrict__ mids, const float* __restrict__ widths,
        const int* __restrict__ g_count,
        const unsigned short* __restrict__ lists,
        float* __restrict__ out) {
    __shared__ short wbuf[2][8192];           // 32KB: W1 dbuf; then hbuf=wbuf[0], W2 halves=wbuf[1]
    __shared__ float lds_B4[NF * 4];          // 2KB  B rows padded [f][4]
    __shared__ float xp[PTS_PER_BLK][6];      // 1.5KB
    __shared__ int   ns[PTS_PER_BLK];
    __shared__ int   sprefix[NSLAB + 1];

    int t = threadIdx.x;

    // inline work-table: prefix of ceil(g_count[s]/64)
    if (t == 0) {
        int acc = 0;
        #pragma unroll
        for (int ss = 0; ss < NSLAB; ++ss) {
            sprefix[ss] = acc;
            acc += (g_count[ss] + PTS_PER_BLK - 1) >> 6;
        }
        sprefix[NSLAB] = acc;
    }
    __syncthreads();
    if ((int)blockIdx.x >= sprefix[NSLAB]) return;
    int s = 0;
    while (s < NSLAB - 1 && (int)blockIdx.x >= sprefix[s + 1]) ++s;
    int pbase = ((int)blockIdx.x - sprefix[s]) * PTS_PER_BLK;
    int count = g_count[s];

    int w = t >> 6;          // wave id -> point group
    int l = t & 63;
    int p = l & 15;          // point within wave group / n&15 for A rows
    int khi = l >> 4;        // 0..3

    float mid = mids[s], wd = widths[s];
    if (t < PTS_PER_BLK) {
        int idx = pbase + t;
        int ii = idx < count ? idx : count - 1;
        int n = lists[s * NPTS + ii];
        ns[t] = n;
        const float* xr = x + n * 6;
        #pragma unroll
        for (int d = 0; d < 6; ++d) xp[t][d] = (xr[d] - mid) / wd;
    }
    if (t < NF) {
        const float* br = B + s * (NF * 3) + t * 3;
        ((f32x4*)lds_B4)[t] = (f32x4){br[0], br[1], br[2], 0.0f};
    }

    const unsigned short* W1Ts = W1T + (size_t)s * HDIM * KDIM;
    const unsigned short* W2Ts = W2T + (size_t)s * HDIM * HDIM;
    const float* b1s = b1 + s * HDIM;
    const float* b2s = b2 + s * HDIM;
    const float* W3s = W3 + s * HDIM;
    float b3s = b3[s];

    // T14 split staging: issue loads early (regs), write to LDS late.
    #define STAGE_LOAD(regs, c)                                                    \
    do {                                                                           \
        _Pragma("unroll")                                                          \
        for (int ps = 0; ps < 4; ++ps) {                                           \
            int tq = ps * 256 + t;                                                 \
            int n_ = tq >> 3;                                                      \
            int o_ = (tq & 7) * 16;                                                \
            regs[ps] = *(const u32x4*)((const char*)W1Ts + (size_t)n_ * 1024       \
                                       + (c) * 128 + o_);                          \
        }                                                                          \
    } while (0)

    #define STAGE_WRITE(regs, c)                                                   \
    do {                                                                           \
        char* dst = (char*)wbuf[(c) & 1];                                          \
        _Pragma("unroll")                                                          \
        for (int ps = 0; ps < 4; ++ps) {                                           \
            int tq = ps * 256 + t;                                                 \
            int n_ = tq >> 3;                                                      \
            int o_ = (tq & 7) * 16;                                                \
            unsigned lb = (unsigned)(n_ * 128 + o_) ^ ((unsigned)(n_ & 7) << 4);   \
            *(u32x4*)(dst + lb) = regs[ps];                                        \
        }                                                                          \
    } while (0)

    #define W2_LOAD(regs, h)                                                       \
    do {                                                                           \
        _Pragma("unroll")                                                          \
        for (int ps = 0; ps < 4; ++ps) {                                           \
            int tq = ps * 256 + t;                                                 \
            int n_ = tq >> 3;                                                      \
            int o_ = (tq & 7) * 16;                                                \
            regs[ps] = *(const u32x4*)((const char*)W2Ts + (size_t)n_ * 256        \
                                       + (h) * 128 + o_);                          \
        }                                                                          \
    } while (0)

    #define W2_WRITE(regs)                                                         \
    do {                                                                           \
        char* dst = (char*)wbuf[1];                                                \
        _Pragma("unroll")                                                          \
        for (int ps = 0; ps < 4; ++ps) {                                           \
            int tq = ps * 256 + t;                                                 \
            int n_ = tq >> 3;                                                      \
            int o_ = (tq & 7) * 16;                                                \
            unsigned lb = (unsigned)(n_ * 128 + o_) ^ ((unsigned)(n_ & 7) << 4);   \
            *(u32x4*)(dst + lb) = regs[ps];                                        \
        }                                                                          \
    } while (0)

    u32x4 stg[4];
    STAGE_LOAD(stg, 0);
    STAGE_WRITE(stg, 0);
    __syncthreads();

    int pt = w * 16 + p;
    float xv0 = xp[pt][0], xv1 = xp[pt][1], xv2 = xp[pt][2];
    float xv3 = xp[pt][3], xv4 = xp[pt][4], xv5 = xp[pt][5];

    // ---- layer 1: D1[col][pt] over K'=512 (k' = f*4+type), r17-proven ----
    f32x4 acc1[8];
    #pragma unroll
    for (int nt = 0; nt < 8; ++nt)
        acc1[nt] = *(const f32x4*)(b1s + nt * 16 + khi * 4);

    #define COMPUTE_W1(c)                                                          \
    do {                                                                           \
        const char* wb = (const char*)wbuf[(c) & 1];                               \
        _Pragma("unroll")                                                          \
        for (int kl = 0; kl < 2; ++kl) {                                           \
            int ks = 2 * (c) + kl;                                                 \
            int f0 = ks * 8 + khi * 2;                                             \
            f32x4 Ba = ((const f32x4*)lds_B4)[f0];                                 \
            f32x4 Bb = ((const f32x4*)lds_B4)[f0 + 1];                             \
            float Fa0 = xv0 * Ba.x + xv1 * Ba.y + xv2 * Ba.z;                      \
            float Fa1 = xv3 * Ba.x + xv4 * Ba.y + xv5 * Ba.z;                      \
            float Fb0 = xv0 * Bb.x + xv1 * Bb.y + xv2 * Bb.z;                      \
            float Fb1 = xv3 * Bb.x + xv4 * Bb.y + xv5 * Bb.z;                      \
            float pa0 = __builtin_amdgcn_fractf(Fa0);                              \
            float pa1 = __builtin_amdgcn_fractf(Fa1);                              \
            float pb0 = __builtin_amdgcn_fractf(Fb0);                              \
            float pb1 = __builtin_amdgcn_fractf(Fb1);                              \
            unsigned k0 = pk_bf16(__builtin_amdgcn_sinf(pa0), __builtin_amdgcn_cosf(pa0)); \
            unsigned k1 = pk_bf16(__builtin_amdgcn_sinf(pa1), __builtin_amdgcn_cosf(pa1)); \
            unsigned k2 = pk_bf16(__builtin_amdgcn_sinf(pb0), __builtin_amdgcn_cosf(pb0)); \
            unsigned k3 = pk_bf16(__builtin_amdgcn_sinf(pb1), __builtin_amdgcn_cosf(pb1)); \
            u32x4 bu = (u32x4){k0, k1, k2, k3};                                    \
            bf16x8 bfr;                                                            \
            __builtin_memcpy(&bfr, &bu, 16);                                       \
            _Pragma("unroll")                                                      \
            for (int nt = 0; nt < 8; ++nt) {                                       \
                int n_ = nt * 16 + p;                                              \
                unsigned byte = (unsigned)(n_ * 128 + kl * 64 + khi * 16)          \
                              ^ ((unsigned)(n_ & 7) << 4);                         \
                bf16x8 af = *(const bf16x8*)(wb + byte);                           \
                acc1[nt] = __builtin_amdgcn_mfma_f32_16x16x32_bf16(                \
                    af, bfr, acc1[nt], 0, 0, 0);                                   \
            }                                                                      \
        }                                                                          \
    } while (0)

    #pragma unroll
    for (int c = 0; c < 7; ++c) {
        STAGE_LOAD(stg, c + 1);              // loads in flight during compute
        COMPUTE_W1(c);
        STAGE_WRITE(stg, c + 1);             // vmcnt drained here, after compute
        __syncthreads();
    }

    // peeled chunk 7: W2 half0 loads issued first (hide under COMPUTE + pack)
    u32x4 sw[4];
    W2_LOAD(sw, 0);
    COMPUTE_W1(7);                           // reads wbuf[1]

    // tanh -> bf16 pack -> wave-private h1T staging in wbuf[0].
    // No barrier needed before this: cross-wave reads of wbuf[0] ended at the
    // c=6 barrier, and this region is only ever read by this wave.
    short* hb = (short*)((char*)wbuf[0] + w * 4096);
    unsigned swzp = ((unsigned)(p & 7)) << 4;
    #pragma unroll
    for (int nt = 0; nt < 8; ++nt) {
        float t0 = fast_tanh(acc1[nt][0]);
        float t1 = fast_tanh(acc1[nt][1]);
        float t2 = fast_tanh(acc1[nt][2]);
        float t3 = fast_tanh(acc1[nt][3]);
        unsigned q0 = pk_bf16(t0, t1), q1 = pk_bf16(t2, t3);
        unsigned byte = ((unsigned)(p * 256 + nt * 32 + khi * 8)) ^ swzp;
        *(u32x2*)((char*)hb + byte) = (u32x2){q0, q1};
    }
    __syncthreads();   // all waves done reading wbuf[1] (chunk 7)
    W2_WRITE(sw);      // half0 into wbuf[1]
    W2_LOAD(sw, 1);    // half1 loads in flight across the next barrier + MFMAs
    __syncthreads();   // half0 visible

    // ---- layer 2: D2[col2][pt] = W2(LDS halves) x h1T(hbuf) ----
    f32x4 acc2[8];
    #pragma unroll
    for (int mt = 0; mt < 8; ++mt)
        acc2[mt] = *(const f32x4*)(b2s + mt * 16 + khi * 4);

    #define MFMA_W2(ks)                                                            \
    do {                                                                           \
        int kl = (ks) & 1;                                                         \
        unsigned rbyte = ((unsigned)(p * 256 + (ks) * 64 + khi * 16)) ^ swzp;      \
        bf16x8 bh = *(const bf16x8*)((const char*)hb + rbyte);                     \
        const char* wb2 = (const char*)wbuf[1];                                    \
        _Pragma("unroll")                                                          \
        for (int mt = 0; mt < 8; ++mt) {                                           \
            int n2 = mt * 16 + p;                                                  \
            unsigned byte = (unsigned)(n2 * 128 + kl * 64 + khi * 16)              \
                          ^ ((unsigned)(n2 & 7) << 4);                             \
            bf16x8 aw = *(const bf16x8*)(wb2 + byte);                              \
            acc2[mt] = __builtin_amdgcn_mfma_f32_16x16x32_bf16(                    \
                aw, bh, acc2[mt], 0, 0, 0);                                        \
        }                                                                          \
    } while (0)

    MFMA_W2(0);
    MFMA_W2(1);
    __syncthreads();   // all reads of half0 done
    W2_WRITE(sw);      // half1
    __syncthreads();   // half1 visible
    MFMA_W2(2);
    MFMA_W2(3);

    // ---- layer 3 + fused finalize ----
    float part = 0.0f;
    #pragma unroll
    for (int mt = 0; mt < 8; ++mt) {
        f32x4 w3v = *(const f32x4*)(W3s + mt * 16 + khi * 4);
        part += fast_tanh(acc2[mt][0]) * w3v.x;
        part += fast_tanh(acc2[mt][1]) * w3v.y;
        part += fast_tanh(acc2[mt][2]) * w3v.z;
        part += fast_tanh(acc2[mt][3]) * w3v.w;
    }
    part += __shfl_xor(part, 16, 64);
    part += __shfl_xor(part, 32, 64);
    if (l < 16) {
        int idx = pbase + w * 16 + l;
        if (idx < count) {
            int n = ns[w * 16 + l];
            float tau = part + b3s;
            float xc = x[n * 6];
            float den = 0.0f, wgt = 0.0f;
            #pragma unroll
            for (int ss = 0; ss < NSLAB; ++ss) {
                float xmin = mids[ss] - 0.5f * widths[ss];
                float xmax = mids[ss] + 0.5f * widths[ss];
                if (xc >= xmin && xc <= xmax) {
                    float xs_ = 2.0f * (xc - xmin) / (xmax - xmin) - 1.0f;
                    float wv = 0.5f * (1.0f + __builtin_amdgcn_cosf(__builtin_amdgcn_fractf(0.5f * xs_)));
                    den += wv;
                    if (ss == s) wgt = wv;
                }
            }
            atomicAdd(out + n, wgt * tau / den);
        }
    }
}

extern "C" void kernel_launch(void* const* d_in, const int* in_sizes, int n_in,
                              void* d_out, int out_size, void* d_ws, size_t ws_size,
                              hipStream_t stream) {
    const float* x      = (const float*)d_in[0];
    const float* B      = (const float*)d_in[1];
    const float* W1     = (const float*)d_in[2];
    const float* b1     = (const float*)d_in[3];
    const float* W2     = (const float*)d_in[4];
    const float* b2     = (const float*)d_in[5];
    const float* W3     = (const float*)d_in[6];
    const float* b3     = (const float*)d_in[7];
    const float* mids   = (const float*)d_in[8];
    const float* widths = (const float*)d_in[9];
    float* out = (float*)d_out;

    char* ws = (char*)d_ws;
    int*            g_count = (int*)(ws + WS_COUNT_OFF);
    unsigned short* lists   = (unsigned short*)(ws + WS_LIST_OFF);
    unsigned short* W1T     = (unsigned short*)(ws + WS_W1T_OFF);
    unsigned short* W2T     = (unsigned short*)(ws + WS_W2T_OFF);

    prep_weights<<<dim3(80, NSLAB), 256, 0, stream>>>(W1, W2, W1T, W2T, g_count);
    build_lists<<<dim3(NPTS / 256), 256, 0, stream>>>(x, mids, widths, g_count, lists, out);
    mlp_eval<<<dim3(MAXBLK), 256, 0, stream>>>(
        x, B, W1T, b1, W2T, b2, W3, b3, mids, widths, g_count, lists, out);
}

// Round 25
// 49.369 us; speedup vs baseline: 1.0109x; 1.0109x over previous
//
#include <hip/hip_runtime.h>
#include <hip/hip_bf16.h>

#define NPTS 32768
#define NSLAB 16
#define NF 128
#define HDIM 128
#define KDIM 512          // 4*NF
#define PTS_PER_BLK 64
#define MAXBLK 2064       // sum ceil(count_s/64) <= 4*32768/64 + 16

// ---- workspace layout (bytes) ----
// [0, 64)        : g_count[16] (int)
// [1024, +1MB)   : lists, u16 [16][NPTS]
// [4MB, 6MB)     : W1T bf16 [16][128][512]  (K-permuted: k' = f*4+type)
// [6MB, 6.5MB)   : W2T bf16 [16][128][128]
#define WS_COUNT_OFF   0
#define WS_LIST_OFF    1024
#define WS_W1T_OFF     (4u << 20)
#define WS_W2T_OFF     (6u << 20)

typedef __attribute__((ext_vector_type(8))) short bf16x8;
typedef __attribute__((ext_vector_type(4))) float f32x4;
typedef __attribute__((ext_vector_type(4))) unsigned int u32x4;
typedef __attribute__((ext_vector_type(2))) unsigned int u32x2;

__device__ __forceinline__ unsigned short f2bf(float f) {
    union { float f; unsigned u; } v; v.f = f;
    unsigned u = v.u;
    return (unsigned short)((u + 0x7FFFu + ((u >> 16) & 1u)) >> 16);
}
__device__ __forceinline__ float fast_tanh(float v) {
    v = fminf(fmaxf(v, -15.0f), 15.0f);
    float t = __builtin_amdgcn_exp2f(v * 2.8853900817779268f); // e^{2v}
    return (t - 1.0f) * __builtin_amdgcn_rcpf(t + 1.0f);
}
// pack two f32 -> one u32 of two bf16 (lo = a, hi = b)
__device__ __forceinline__ unsigned pk_bf16(float a, float b) {
    unsigned r;
    asm("v_cvt_pk_bf16_f32 %0, %1, %2" : "=v"(r) : "v"(a), "v"(b));
    return r;
}

// Transpose + f32->bf16 for W1 (K-permuted) and W2 in one launch (r13/r15-proven).
// Also zeroes g_count (runs before build_lists on the stream).
__global__ void prep_weights(const float* __restrict__ W1, const float* __restrict__ W2,
                             unsigned short* __restrict__ W1T, unsigned short* __restrict__ W2T,
                             int* __restrict__ g_count) {
    if (blockIdx.x == 0 && blockIdx.y == 0 && threadIdx.x < NSLAB)
        g_count[threadIdx.x] = 0;
    __shared__ float tl[32][33];
    int s = blockIdx.y;
    int bt = blockIdx.x;
    const float* in; unsigned short* out; int K, N, perm, tk, tn;
    if (bt < 64) { in = W1; out = W1T; K = KDIM; N = HDIM; perm = 1; tk = bt >> 2; tn = bt & 3; }
    else         { bt -= 64; in = W2; out = W2T; K = HDIM; N = HDIM; perm = 0; tk = bt >> 2; tn = bt & 3; }
    const float* ins = in + (size_t)s * K * N;
    unsigned short* outs = out + (size_t)s * N * K;
    int t = threadIdx.x, r4 = t >> 5, c = t & 31;
    #pragma unroll
    for (int i = 0; i < 4; ++i) {
        int r = i * 8 + r4;
        tl[r][c] = ins[(tk * 32 + r) * N + tn * 32 + c];
    }
    __syncthreads();
    #pragma unroll
    for (int i = 0; i < 4; ++i) {
        int r = i * 8 + r4;
        int k = tk * 32 + c;
        int kp = perm ? ((k & 127) * 4 + (k >> 7)) : k;
        outs[(size_t)(tn * 32 + r) * K + kp] = f2bf(tl[c][r]);
    }
}

// build_lists also zeroes out[] (stream-ordered before mlp_eval's atomics).
__global__ void build_lists(const float* __restrict__ x,
                            const float* __restrict__ mids,
                            const float* __restrict__ widths,
                            int* __restrict__ g_count,
                            unsigned short* __restrict__ lists,
                            float* __restrict__ out) {
    __shared__ int cnt[NSLAB];
    __shared__ int base[NSLAB];
    int tid = threadIdx.x;
    if (tid < NSLAB) cnt[tid] = 0;
    __syncthreads();
    int n = blockIdx.x * 256 + tid;
    out[n] = 0.0f;
    float xc = x[n * 6];
    int ofs[NSLAB];
    unsigned int amask = 0;
    #pragma unroll
    for (int s = 0; s < NSLAB; ++s) {
        float xmin = mids[s] - 0.5f * widths[s];
        float xmax = mids[s] + 0.5f * widths[s];
        if (xc >= xmin && xc <= xmax) {
            ofs[s] = atomicAdd(&cnt[s], 1);
            amask |= (1u << s);
        }
    }
    __syncthreads();
    if (tid < NSLAB) base[tid] = atomicAdd(&g_count[tid], cnt[tid]);
    __syncthreads();
    #pragma unroll
    for (int s = 0; s < NSLAB; ++s)
        if (amask & (1u << s))
            lists[s * NPTS + base[s] + ofs[s]] = (unsigned short)n;
}

// Block: 256 thr = 4 waves; 64 points x 1 slab. Work item via inline prefix scan.
// r20/r21-proven body. Epilogue fuses finalize: each (slab,point) atomically
// adds w_s*tau/den(n) to out[n]; den is MLP-independent window arithmetic.
__global__ __launch_bounds__(256, 4) void mlp_eval(
        const float* __restrict__ x,  const float* __restrict__ B,
        const unsigned short* __restrict__ W1T, const float* __restrict__ b1,
        const unsigned short* __restrict__ W2T, const float* __restrict__ b2,
        const float* __restrict__ W3, const float* __restrict__ b3,
        const float* __restrict__ mids, const float* __restrict__ widths,
        const int* __restrict__ g_count,
        const unsigned short* __restrict__ lists,
        float* __restrict__ out) {
    __shared__ short wbuf[2][8192];           // 32KB: W1 dbuf; then hbuf=wbuf[0], W2 halves=wbuf[1]
    __shared__ float lds_B4[NF * 4];          // 2KB  B rows padded [f][4]
    __shared__ float xp[PTS_PER_BLK][6];      // 1.5KB
    __shared__ int   ns[PTS_PER_BLK];
    __shared__ int   sprefix[NSLAB + 1];

    int t = threadIdx.x;

    // inline work-table: prefix of ceil(g_count[s]/64)
    if (t == 0) {
        int acc = 0;
        #pragma unroll
        for (int ss = 0; ss < NSLAB; ++ss) {
            sprefix[ss] = acc;
            acc += (g_count[ss] + PTS_PER_BLK - 1) >> 6;
        }
        sprefix[NSLAB] = acc;
    }
    __syncthreads();
    if ((int)blockIdx.x >= sprefix[NSLAB]) return;
    int s = 0;
    while (s < NSLAB - 1 && (int)blockIdx.x >= sprefix[s + 1]) ++s;
    int pbase = ((int)blockIdx.x - sprefix[s]) * PTS_PER_BLK;
    int count = g_count[s];

    int w = t >> 6;          // wave id -> point group
    int l = t & 63;
    int p = l & 15;          // point within wave group / n&15 for A rows
    int khi = l >> 4;        // 0..3

    float mid = mids[s], wd = widths[s];
    if (t < PTS_PER_BLK) {
        int idx = pbase + t;
        int ii = idx < count ? idx : count - 1;
        int n = lists[s * NPTS + ii];
        ns[t] = n;
        const float* xr = x + n * 6;
        #pragma unroll
        for (int d = 0; d < 6; ++d) xp[t][d] = (xr[d] - mid) / wd;
    }
    if (t < NF) {
        const float* br = B + s * (NF * 3) + t * 3;
        ((f32x4*)lds_B4)[t] = (f32x4){br[0], br[1], br[2], 0.0f};
    }

    const unsigned short* W1Ts = W1T + (size_t)s * HDIM * KDIM;
    const unsigned short* W2Ts = W2T + (size_t)s * HDIM * HDIM;
    const float* b1s = b1 + s * HDIM;
    const float* b2s = b2 + s * HDIM;
    const float* W3s = W3 + s * HDIM;
    float b3s = b3[s];

    // T14 split staging: issue loads early (regs), write to LDS late.
    #define STAGE_LOAD(regs, c)                                                    \
    do {                                                                           \
        _Pragma("unroll")                                                          \
        for (int ps = 0; ps < 4; ++ps) {                                           \
            int tq = ps * 256 + t;                                                 \
            int n_ = tq >> 3;                                                      \
            int o_ = (tq & 7) * 16;                                                \
            regs[ps] = *(const u32x4*)((const char*)W1Ts + (size_t)n_ * 1024       \
                                       + (c) * 128 + o_);                          \
        }                                                                          \
    } while (0)

    #define STAGE_WRITE(regs, c)                                                   \
    do {                                                                           \
        char* dst = (char*)wbuf[(c) & 1];                                          \
        _Pragma("unroll")                                                          \
        for (int ps = 0; ps < 4; ++ps) {                                           \
            int tq = ps * 256 + t;                                                 \
            int n_ = tq >> 3;                                                      \
            int o_ = (tq & 7) * 16;                                                \
            unsigned lb = (unsigned)(n_ * 128 + o_) ^ ((unsigned)(n_ & 7) << 4);   \
            *(u32x4*)(dst + lb) = regs[ps];                                        \
        }                                                                          \
    } while (0)

    #define W2_LOAD(regs, h)                                                       \
    do {                                                                           \
        _Pragma("unroll")                                                          \
        for (int ps = 0; ps < 4; ++ps) {                                           \
            int tq = ps * 256 + t;                                                 \
            int n_ = tq >> 3;                                                      \
            int o_ = (tq & 7) * 16;                                                \
            regs[ps] = *(const u32x4*)((const char*)W2Ts + (size_t)n_ * 256        \
                                       + (h) * 128 + o_);                          \
        }                                                                          \
    } while (0)

    #define W2_WRITE(regs)                                                         \
    do {                                                                           \
        char* dst = (char*)wbuf[1];                                                \
        _Pragma("unroll")                                                          \
        for (int ps = 0; ps < 4; ++ps) {                                           \
            int tq = ps * 256 + t;                                                 \
            int n_ = tq >> 3;                                                      \
            int o_ = (tq & 7) * 16;                                                \
            unsigned lb = (unsigned)(n_ * 128 + o_) ^ ((unsigned)(n_ & 7) << 4);   \
            *(u32x4*)(dst + lb) = regs[ps];                                        \
        }                                                                          \
    } while (0)

    u32x4 stg[4];
    STAGE_LOAD(stg, 0);
    STAGE_WRITE(stg, 0);
    __syncthreads();

    int pt = w * 16 + p;
    float xv0 = xp[pt][0], xv1 = xp[pt][1], xv2 = xp[pt][2];
    float xv3 = xp[pt][3], xv4 = xp[pt][4], xv5 = xp[pt][5];

    // ---- layer 1: D1[col][pt] over K'=512 (k' = f*4+type), r17-proven ----
    f32x4 acc1[8];
    #pragma unroll
    for (int nt = 0; nt < 8; ++nt)
        acc1[nt] = *(const f32x4*)(b1s + nt * 16 + khi * 4);

    #define COMPUTE_W1(c)                                                          \
    do {                                                                           \
        const char* wb = (const char*)wbuf[(c) & 1];                               \
        _Pragma("unroll")                                                          \
        for (int kl = 0; kl < 2; ++kl) {                                           \
            int ks = 2 * (c) + kl;                                                 \
            int f0 = ks * 8 + khi * 2;                                             \
            f32x4 Ba = ((const f32x4*)lds_B4)[f0];                                 \
            f32x4 Bb = ((const f32x4*)lds_B4)[f0 + 1];                             \
            float Fa0 = xv0 * Ba.x + xv1 * Ba.y + xv2 * Ba.z;                      \
            float Fa1 = xv3 * Ba.x + xv4 * Ba.y + xv5 * Ba.z;                      \
            float Fb0 = xv0 * Bb.x + xv1 * Bb.y + xv2 * Bb.z;                      \
            float Fb1 = xv3 * Bb.x + xv4 * Bb.y + xv5 * Bb.z;                      \
            float pa0 = __builtin_amdgcn_fractf(Fa0);                              \
            float pa1 = __builtin_amdgcn_fractf(Fa1);                              \
            float pb0 = __builtin_amdgcn_fractf(Fb0);                              \
            float pb1 = __builtin_amdgcn_fractf(Fb1);                              \
            unsigned k0 = pk_bf16(__builtin_amdgcn_sinf(pa0), __builtin_amdgcn_cosf(pa0)); \
            unsigned k1 = pk_bf16(__builtin_amdgcn_sinf(pa1), __builtin_amdgcn_cosf(pa1)); \
            unsigned k2 = pk_bf16(__builtin_amdgcn_sinf(pb0), __builtin_amdgcn_cosf(pb0)); \
            unsigned k3 = pk_bf16(__builtin_amdgcn_sinf(pb1), __builtin_amdgcn_cosf(pb1)); \
            u32x4 bu = (u32x4){k0, k1, k2, k3};                                    \
            bf16x8 bfr;                                                            \
            __builtin_memcpy(&bfr, &bu, 16);                                       \
            __builtin_amdgcn_s_setprio(1);                                         \
            _Pragma("unroll")                                                      \
            for (int nt = 0; nt < 8; ++nt) {                                       \
                int n_ = nt * 16 + p;                                              \
                unsigned byte = (unsigned)(n_ * 128 + kl * 64 + khi * 16)          \
                              ^ ((unsigned)(n_ & 7) << 4);                         \
                bf16x8 af = *(const bf16x8*)(wb + byte);                           \
                acc1[nt] = __builtin_amdgcn_mfma_f32_16x16x32_bf16(                \
                    af, bfr, acc1[nt], 0, 0, 0);                                   \
            }                                                                      \
            __builtin_amdgcn_s_setprio(0);                                         \
        }                                                                          \
    } while (0)

    #pragma unroll
    for (int c = 0; c < 8; ++c) {
        if (c < 7) STAGE_LOAD(stg, c + 1);   // loads in flight during compute
        COMPUTE_W1(c);
        if (c < 7) STAGE_WRITE(stg, c + 1);  // vmcnt drained here, after compute
        __syncthreads();
    }
    // wbuf fully dead: wbuf[0] -> hbuf, wbuf[1] -> W2 halves

    u32x4 sw[4];
    W2_LOAD(sw, 0);          // lands during tanh-pack below

    // tanh -> bf16 pack -> wave-private h1T staging in wbuf[0] (r18/r19-proven)
    short* hb = (short*)((char*)wbuf[0] + w * 4096);
    unsigned swzp = ((unsigned)(p & 7)) << 4;
    #pragma unroll
    for (int nt = 0; nt < 8; ++nt) {
        float t0 = fast_tanh(acc1[nt][0]);
        float t1 = fast_tanh(acc1[nt][1]);
        float t2 = fast_tanh(acc1[nt][2]);
        float t3 = fast_tanh(acc1[nt][3]);
        unsigned q0 = pk_bf16(t0, t1), q1 = pk_bf16(t2, t3);
        unsigned byte = ((unsigned)(p * 256 + nt * 32 + khi * 8)) ^ swzp;
        *(u32x2*)((char*)hb + byte) = (u32x2){q0, q1};
    }
    W2_WRITE(sw);
    __syncthreads();   // W2 half0 visible

    // ---- layer 2: D2[col2][pt] = W2(LDS halves) x h1T(hbuf) ----
    f32x4 acc2[8];
    #pragma unroll
    for (int mt = 0; mt < 8; ++mt)
        acc2[mt] = *(const f32x4*)(b2s + mt * 16 + khi * 4);

    #define MFMA_W2(ks)                                                            \
    do {                                                                           \
        int kl = (ks) & 1;                                                         \
        unsigned rbyte = ((unsigned)(p * 256 + (ks) * 64 + khi * 16)) ^ swzp;      \
        bf16x8 bh = *(const bf16x8*)((const char*)hb + rbyte);                     \
        const char* wb2 = (const char*)wbuf[1];                                    \
        __builtin_amdgcn_s_setprio(1);                                             \
        _Pragma("unroll")                                                          \
        for (int mt = 0; mt < 8; ++mt) {                                           \
            int n2 = mt * 16 + p;                                                  \
            unsigned byte = (unsigned)(n2 * 128 + kl * 64 + khi * 16)              \
                          ^ ((unsigned)(n2 & 7) << 4);                             \
            bf16x8 aw = *(const bf16x8*)(wb2 + byte);                              \
            acc2[mt] = __builtin_amdgcn_mfma_f32_16x16x32_bf16(                    \
                aw, bh, acc2[mt], 0, 0, 0);                                        \
        }                                                                          \
        __builtin_amdgcn_s_setprio(0);                                             \
    } while (0)

    W2_LOAD(sw, 1);          // half1 loads in flight during MFMA ks 0,1
    MFMA_W2(0);
    MFMA_W2(1);
    __syncthreads();   // all reads of half0 done
    W2_WRITE(sw);
    __syncthreads();   // half1 visible
    MFMA_W2(2);
    MFMA_W2(3);

    // ---- layer 3 + fused finalize ----
    float part = 0.0f;
    #pragma unroll
    for (int mt = 0; mt < 8; ++mt) {
        f32x4 w3v = *(const f32x4*)(W3s + mt * 16 + khi * 4);
        part += fast_tanh(acc2[mt][0]) * w3v.x;
        part += fast_tanh(acc2[mt][1]) * w3v.y;
        part += fast_tanh(acc2[mt][2]) * w3v.z;
        part += fast_tanh(acc2[mt][3]) * w3v.w;
    }
    part += __shfl_xor(part, 16, 64);
    part += __shfl_xor(part, 32, 64);
    if (l < 16) {
        int idx = pbase + w * 16 + l;
        if (idx < count) {
            int n = ns[w * 16 + l];
            float tau = part + b3s;
            float xc = x[n * 6];
            float den = 0.0f, wgt = 0.0f;
            #pragma unroll
            for (int ss = 0; ss < NSLAB; ++ss) {
                float xmin = mids[ss] - 0.5f * widths[ss];
                float xmax = mids[ss] + 0.5f * widths[ss];
                if (xc >= xmin && xc <= xmax) {
                    float xs_ = 2.0f * (xc - xmin) / (xmax - xmin) - 1.0f;
                    float wv = 0.5f * (1.0f + __builtin_amdgcn_cosf(__builtin_amdgcn_fractf(0.5f * xs_)));
                    den += wv;
                    if (ss == s) wgt = wv;
                }
            }
            atomicAdd(out + n, wgt * tau / den);
        }
    }
}

extern "C" void kernel_launch(void* const* d_in, const int* in_sizes, int n_in,
                              void* d_out, int out_size, void* d_ws, size_t ws_size,
                              hipStream_t stream) {
    const float* x      = (const float*)d_in[0];
    const float* B      = (const float*)d_in[1];
    const float* W1     = (const float*)d_in[2];
    const float* b1     = (const float*)d_in[3];
    const float* W2     = (const float*)d_in[4];
    const float* b2     = (const float*)d_in[5];
    const float* W3     = (const float*)d_in[6];
    const float* b3     = (const float*)d_in[7];
    const float* mids   = (const float*)d_in[8];
    const float* widths = (const float*)d_in[9];
    float* out = (float*)d_out;

    char* ws = (char*)d_ws;
    int*            g_count = (int*)(ws + WS_COUNT_OFF);
    unsigned short* lists   = (unsigned short*)(ws + WS_LIST_OFF);
    unsigned short* W1T     = (unsigned short*)(ws + WS_W1T_OFF);
    unsigned short* W2T     = (unsigned short*)(ws + WS_W2T_OFF);

    prep_weights<<<dim3(80, NSLAB), 256, 0, stream>>>(W1, W2, W1T, W2T, g_count);
    build_lists<<<dim3(NPTS / 256), 256, 0, stream>>>(x, mids, widths, g_count, lists, out);
    mlp_eval<<<dim3(MAXBLK), 256, 0, stream>>>(
        x, B, W1T, b1, W2T, b2, W3, b3, mids, widths, g_count, lists, out);
}